// Round 2
// baseline (21.221 us; speedup 1.0000x reference)
//
#include <hip/hip_runtime.h>

namespace {

constexpr int B_ = 4, C_ = 64, H_ = 96, W_ = 192, S_ = 12;
constexpr int HW = H_ * W_;
constexpr float TEMP_OVER_C = 7.0f / 64.0f;   // TEMPERATURE / C
constexpr int OUT_HALF = B_ * 4 * H_ * W_;    // ndisp_out first, then disp_out
constexpr int WBLK = 96;                      // w-columns per block
constexpr int STRIDE = 144;                   // LDS row capacity (cols)

// per-16-channel-group skew of +4 floats keeps the 4 same-w lanes on
// different banks (16*144 % 32 == 0 would otherwise 4-way conflict)
__device__ __forceinline__ int ldsoff(int c, int j) {
  return c * STRIDE + ((c >> 4) << 2) + j;
}

__global__ __launch_bounds__(384) void fused_eval(
    const float* __restrict__ left, const float* __restrict__ right,
    const float* __restrict__ disp, const float* __restrict__ ndisp,
    float* __restrict__ out)
{
  __shared__ float rlds[C_ * STRIDE + 16];   // ~36.9 KB

  // XCD-bijective swizzle: 768 = 8 * 96, keep (row-half) pairs on one XCD
  const int blk = (blockIdx.x & 7) * 96 + (blockIdx.x >> 3);
  const int half = blk & 1;
  const int bh = blk >> 1;
  const int b = bh / H_;
  const int h = bh - b * H_;
  const int w0 = half * WBLK;
  const int s0 = half ? (w0 - 48) : 0;     // first staged right column
  const int cnt = half ? 144 : 96;         // staged column count

  const int t = threadIdx.x;
  const int l = t & 63;
  const int v = t >> 6;                    // wave 0..5
  const int wl = v * 16 + (l & 15);        // 0..95
  const int g = (l >> 4) & 3;              // channel group / interval id
  const int w = w0 + wl;

  // ---- stage right[b, :, h, s0:s0+cnt] into LDS (float4, coalesced) ----
  const float* rrow = right + (size_t)b * C_ * HW + (size_t)h * W_ + s0;
  {
    const int cpr = cnt >> 2;              // float4 per channel row: 24 or 36
    const int c = t / 6;                   // 6 threads per channel row
    const int t6 = t - c * 6;
    #pragma unroll
    for (int k = 0; k < 6; ++k) {
      const int w4 = t6 + 6 * k;
      if (w4 < cpr) {
        const float4 val = *reinterpret_cast<const float4*>(rrow + (size_t)c * HW + 4 * w4);
        *reinterpret_cast<float4*>(&rlds[ldsoff(c, 4 * w4)]) = val;
      }
    }
  }

  // ---- per-thread setup (overlaps staging latency) ----
  float dsp[S_]; int jdx[S_]; float st[S_];
  #pragma unroll
  for (int s = 0; s < S_; ++s) {
    dsp[s] = disp[((size_t)(b * S_ + s) * H_ + h) * W_ + w];
    // reference: clip(w - d, 0, W-1) in f32, then int32 truncation
    const float ry = fminf(fmaxf((float)w - dsp[s], 0.0f), (float)(W_ - 1));
    jdx[s] = (int)ry - s0;
    st[s] = 0.0f;
  }
  const int c0 = g * 16;
  const float* lcol = left + (size_t)b * C_ * HW + (size_t)h * W_ + w;
  float lreg[16];
  #pragma unroll
  for (int cc = 0; cc < 16; ++cc)
    lreg[cc] = lcol[(size_t)(c0 + cc) * HW];

  __syncthreads();

  // ---- partial dot over this lane's 16 channels, 12 samples ----
  const int base = ldsoff(c0, 0);
  #pragma unroll
  for (int s = 0; s < S_; ++s) {
    const float* rb = &rlds[base + jdx[s]];
    float acc = 0.0f;
    #pragma unroll
    for (int cc = 0; cc < 16; ++cc)
      acc = fmaf(lreg[cc], rb[cc * STRIDE], acc);
    st[s] = acc;
  }

  // ---- butterfly reduce across the 4 channel groups (lanes ^16, ^32) ----
  #pragma unroll
  for (int s = 0; s < S_; ++s) {
    float x = st[s];
    x += __shfl_xor(x, 16, 64);
    x += __shfl_xor(x, 32, 64);
    st[s] = x;
  }

  // ---- epilogue: lane's interval = g; static-index selects (no scratch) ----
  #define SEL4(x0, x3, x6, x9) (g < 2 ? (g == 0 ? (x0) : (x3)) : (g == 2 ? (x6) : (x9)))
  const float a0 = SEL4(st[0], st[3], st[6], st[9])  * TEMP_OVER_C;
  const float a1 = SEL4(st[1], st[4], st[7], st[10]) * TEMP_OVER_C;
  const float a2 = SEL4(st[2], st[5], st[8], st[11]) * TEMP_OVER_C;
  const float d0 = SEL4(dsp[0], dsp[3], dsp[6], dsp[9]);
  const float d1 = SEL4(dsp[1], dsp[4], dsp[7], dsp[10]);
  const float d2 = SEL4(dsp[2], dsp[5], dsp[8], dsp[11]);
  #undef SEL4

  const float m  = fmaxf(a0, fmaxf(a1, a2));
  const float e0 = __expf(a0 - m);
  const float e1 = __expf(a1 - m);
  const float e2 = __expf(a2 - m);
  const float inv = 1.0f / (e0 + e1 + e2);
  const float w0_ = e0 * inv, w1_ = e1 * inv, w2_ = e2 * inv;

  const size_t nbase = ((size_t)(b * S_ + 3 * g) * H_ + h) * W_ + w;
  const float n0 = ndisp[nbase];
  const float n1 = ndisp[nbase + HW];
  const float n2 = ndisp[nbase + 2 * HW];

  const size_t o = ((size_t)(b * 4 + g) * H_ + h) * W_ + w;
  out[o]            = n0 * w0_ + n1 * w1_ + n2 * w2_;   // ndisp_out
  out[OUT_HALF + o] = d0 * w0_ + d1 * w1_ + d2 * w2_;   // disp_out
}

} // namespace

extern "C" void kernel_launch(void* const* d_in, const int* in_sizes, int n_in,
                              void* d_out, int out_size, void* d_ws, size_t ws_size,
                              hipStream_t stream) {
  const float* left  = (const float*)d_in[0];
  const float* right = (const float*)d_in[1];
  const float* disp  = (const float*)d_in[2];
  const float* ndisp = (const float*)d_in[3];
  float* out = (float*)d_out;
  dim3 grid(B_ * H_ * 2);
  dim3 block(384);
  hipLaunchKernelGGL(fused_eval, grid, block, 0, stream, left, right, disp, ndisp, out);
}

// Round 3
// 14.662 us; speedup vs baseline: 1.4474x; 1.4474x over previous
//
#include <hip/hip_runtime.h>

namespace {

constexpr int B_ = 4, C_ = 64, H_ = 96, W_ = 192, S_ = 12;
constexpr int HW = H_ * W_;
constexpr float TEMP_OVER_C = 7.0f / 64.0f;   // TEMPERATURE / C
constexpr int OUT_HALF = B_ * 4 * H_ * W_;    // ndisp_out first, then disp_out
constexpr int LSTR = 68;                      // LDS row stride (floats): 68%32=4 -> bank spread

// Gather one 16-channel chunk for all 6 samples: 4 x ds_read_b128 each.
#define GATHER_CHUNK(LR, C0)                                              \
  {                                                                       \
    _Pragma("unroll")                                                     \
    for (int s = 0; s < 6; ++s) {                                         \
      const float* rr = rp[s] + (C0);                                     \
      const float4 r0 = *reinterpret_cast<const float4*>(rr);             \
      const float4 r1 = *reinterpret_cast<const float4*>(rr + 4);         \
      const float4 r2 = *reinterpret_cast<const float4*>(rr + 8);         \
      const float4 r3 = *reinterpret_cast<const float4*>(rr + 12);        \
      float a = st[s];                                                    \
      a = fmaf(LR[0],  r0.x, a);  a = fmaf(LR[1],  r0.y, a);              \
      a = fmaf(LR[2],  r0.z, a);  a = fmaf(LR[3],  r0.w, a);              \
      a = fmaf(LR[4],  r1.x, a);  a = fmaf(LR[5],  r1.y, a);              \
      a = fmaf(LR[6],  r1.z, a);  a = fmaf(LR[7],  r1.w, a);              \
      a = fmaf(LR[8],  r2.x, a);  a = fmaf(LR[9],  r2.y, a);              \
      a = fmaf(LR[10], r2.z, a);  a = fmaf(LR[11], r2.w, a);              \
      a = fmaf(LR[12], r3.x, a);  a = fmaf(LR[13], r3.y, a);              \
      a = fmaf(LR[14], r3.z, a);  a = fmaf(LR[15], r3.w, a);              \
      st[s] = a;                                                          \
    }                                                                     \
  }

__global__ __launch_bounds__(192) void fused_eval(
    const float* __restrict__ left, const float* __restrict__ right,
    const float* __restrict__ disp, const float* __restrict__ ndisp,
    float* __restrict__ out)
{
  __shared__ float rlds[144 * LSTR];   // 39168 B -> 4 blocks/CU

  // grid 768: bid and bid+384 are the two halves of one (b,h) row.
  // 384 % 8 == 0 -> both land on the same XCD slot under round-robin.
  const int bid = blockIdx.x;
  const int half = (bid >= 384) ? 1 : 0;
  const int bh = bid - half * 384;
  const int b = bh / H_;
  const int h = bh - b * H_;
  const int w0 = half * 96;
  const int s0g = half ? 48 : 0;          // first staged right column
  const int cnt = half ? 144 : 96;        // staged column count

  const int t = threadIdx.x;              // 0..191
  const int shalf = (t >= 96) ? 1 : 0;    // sample half: s 0..5 or 6..11
  const int wl = t - shalf * 96;          // 0..95
  const int w = w0 + wl;

  // ---- stage right[b, :, h, s0g:s0g+cnt] transposed into LDS [col][chan] ----
  // scalar global loads (coalesced across lanes), ds_write_b128 per 4 channels
  const float* rbase = right + (size_t)b * C_ * HW + (size_t)h * W_ + s0g;
  if (t < cnt) {
    float* dst = &rlds[t * LSTR];
    #pragma unroll
    for (int k = 0; k < 16; ++k) {
      float4 v;
      v.x = rbase[(size_t)(4 * k + 0) * HW + t];
      v.y = rbase[(size_t)(4 * k + 1) * HW + t];
      v.z = rbase[(size_t)(4 * k + 2) * HW + t];
      v.w = rbase[(size_t)(4 * k + 3) * HW + t];
      *reinterpret_cast<float4*>(dst + 4 * k) = v;
    }
  }

  // ---- per-thread sample setup + first left chunk (issue before barrier) ----
  const float* lcol = left + (size_t)b * C_ * HW + (size_t)h * W_ + w;
  float la[16], lb[16];
  #pragma unroll
  for (int c = 0; c < 16; ++c) la[c] = lcol[(size_t)c * HW];

  const int sb = 6 * shalf;
  float dsp[6], nds[6];
  int jdx[6];
  const size_t dbase = ((size_t)(b * S_ + sb) * H_ + h) * W_ + w;
  #pragma unroll
  for (int s = 0; s < 6; ++s) {
    dsp[s] = disp[dbase + (size_t)s * HW];
    nds[s] = ndisp[dbase + (size_t)s * HW];
    // reference: clip(w - d, 0, W-1) in f32, then int32 truncation
    const float ry = fminf(fmaxf((float)w - dsp[s], 0.0f), (float)(W_ - 1));
    jdx[s] = (int)ry - s0g;
  }

  __syncthreads();

  // ---- full 64-channel dot per thread, 6 samples, b128 LDS gathers ----
  const float* rp[6];
  #pragma unroll
  for (int s = 0; s < 6; ++s) rp[s] = &rlds[jdx[s] * LSTR];

  float st[6] = {0.f, 0.f, 0.f, 0.f, 0.f, 0.f};

  #pragma unroll
  for (int c = 0; c < 16; ++c) lb[c] = lcol[(size_t)(16 + c) * HW];
  GATHER_CHUNK(la, 0)
  #pragma unroll
  for (int c = 0; c < 16; ++c) la[c] = lcol[(size_t)(32 + c) * HW];
  GATHER_CHUNK(lb, 16)
  #pragma unroll
  for (int c = 0; c < 16; ++c) lb[c] = lcol[(size_t)(48 + c) * HW];
  GATHER_CHUNK(la, 32)
  GATHER_CHUNK(lb, 48)

  // ---- epilogue: 2 intervals per thread, fully static ----
  #pragma unroll
  for (int ii = 0; ii < 2; ++ii) {
    const float a0 = st[3 * ii + 0] * TEMP_OVER_C;
    const float a1 = st[3 * ii + 1] * TEMP_OVER_C;
    const float a2 = st[3 * ii + 2] * TEMP_OVER_C;
    const float m  = fmaxf(a0, fmaxf(a1, a2));
    const float e0 = __expf(a0 - m);
    const float e1 = __expf(a1 - m);
    const float e2 = __expf(a2 - m);
    const float inv = 1.0f / (e0 + e1 + e2);
    const int iv = 2 * shalf + ii;
    const size_t o = ((size_t)(b * 4 + iv) * H_ + h) * W_ + w;
    out[o] = (nds[3 * ii] * e0 + nds[3 * ii + 1] * e1 + nds[3 * ii + 2] * e2) * inv;
    out[OUT_HALF + o] =
        (dsp[3 * ii] * e0 + dsp[3 * ii + 1] * e1 + dsp[3 * ii + 2] * e2) * inv;
  }
}

} // namespace

extern "C" void kernel_launch(void* const* d_in, const int* in_sizes, int n_in,
                              void* d_out, int out_size, void* d_ws, size_t ws_size,
                              hipStream_t stream) {
  const float* left  = (const float*)d_in[0];
  const float* right = (const float*)d_in[1];
  const float* disp  = (const float*)d_in[2];
  const float* ndisp = (const float*)d_in[3];
  float* out = (float*)d_out;
  dim3 grid(2 * B_ * H_);
  dim3 block(192);
  hipLaunchKernelGGL(fused_eval, grid, block, 0, stream, left, right, disp, ndisp, out);
}